// Round 1
// baseline (331.906 us; speedup 1.0000x reference)
//
#include <hip/hip_runtime.h>
#include <math.h>

// GCN 2-layer + sigmoid head. CSR pull-gather, zero fp32 atomics.
// R16: drop k_fb1 + k_scanC entirely. Per-(chunk,bucket) base offsets in the
//      binned region are allocated with a single global atomicAdd on cur[b]
//      (order within a bucket is irrelevant: k_sort re-sorts by node and the
//      downstream sums are bf16-rounded). cur's final values ARE btot.
//      Block scans in k_fillbin/k_sort switched from 16-barrier LDS
//      Hillis-Steele to wave shfl_up scan + 1-barrier wave-sum combine.
//      k_fillbin LDS 37.9->32.0 KB => 5 blk/CU.
//   k_fillbin:LDS chunk counting-sort; chunk base via atomicAdd(&cur[b],cnt)
//   k_sort:   full-bucket reg-cached counting sort -> dense csr, dinv, xdq(bf16)
//   k_gat1/2: node-group gathers (16 lanes/node, bf16 payloads L2-resident)

#define TPB 256
#define NBS 8
#define NBKT 256        // nodes per bucket
#define MAXB 1024       // max buckets (n <= 262144)
#define BPT (MAXB / TPB)
#define CHUNK 4096      // edges per fillbin block
#define EPT (CHUNK / TPB)
#define CAP 9216        // bucket region capacity (mean 8192 + ~11 sigma)
#define RPT (CAP / TPB) // 36 register-cached words per k_sort thread
#define NWAVE (TPB / 64)

__device__ __forceinline__ unsigned short f2bf(float f) {
    unsigned u = __float_as_uint(f);
    unsigned r = (u + 0x7FFFu + ((u >> 16) & 1u)) >> 16;  // RNE
    return (unsigned short)r;
}
__device__ __forceinline__ unsigned pk2(float a, float b) {
    return (unsigned)f2bf(a) | ((unsigned)f2bf(b) << 16);
}
#define BFLO(u) __uint_as_float((u) << 16)
#define BFHI(u) __uint_as_float((u) & 0xFFFF0000u)

// bin edges into fixed-cap bucket regions. LDS counting sort of the chunk;
// chunk's base in each bucket region via one global atomicAdd per non-empty
// bucket. word: ((d&255)<<18)|s
__global__ void __launch_bounds__(TPB) k_fillbin(
        const int* __restrict__ src, const int* __restrict__ dst,
        int* __restrict__ cur, int* __restrict__ binned, int e, int nb) {
    __shared__ int stage[CHUNK];            // 16 KB, bucket-sorted packed words
    __shared__ unsigned short bs[CHUNK];    // 8 KB, bucket id per sorted slot
    __shared__ int h[MAXB];                 // 4 KB, hist -> stage cursor
    __shared__ int delta[MAXB];             // 4 KB
    __shared__ int wsum[NWAVE];
    int t = threadIdx.x;
    int c0 = blockIdx.x * CHUNK;
    int csize = min(e - c0, CHUNK);
#pragma unroll
    for (int k = 0; k < BPT; k++) h[t * BPT + k] = 0;
    __syncthreads();
    int dreg[EPT];
#pragma unroll
    for (int k = 0; k < EPT; k++) {
        int idx = t + k * TPB;               // coalesced
        int d = (idx < csize) ? dst[c0 + idx] : -1;
        dreg[k] = d;
        if (d >= 0) atomicAdd(&h[d >> NBS], 1);
    }
    __syncthreads();
    // per-thread local prefix over its BPT bins
    int loc[BPT], hreg[BPT];
    int ts = 0;
#pragma unroll
    for (int k = 0; k < BPT; k++) {
        hreg[k] = h[t * BPT + k];
        loc[k] = ts;
        ts += hreg[k];
    }
    // block-wide inclusive scan of ts: wave shfl scan + wave-sum combine
    int lane = t & 63, wid = t >> 6;
    int v = ts;
#pragma unroll
    for (int off = 1; off < 64; off <<= 1) {
        int u = __shfl_up(v, off);
        if (lane >= off) v += u;
    }
    if (lane == 63) wsum[wid] = v;
    __syncthreads();
    int pre = 0;
#pragma unroll
    for (int wq = 0; wq < NWAVE - 1; wq++)
        if (wid > wq) pre += wsum[wq];
    int tbase = pre + v - ts;  // exclusive prefix for this thread's first bin
    // per-bucket: stage cursor (excl) + global region base -> delta.
    // (safe to overwrite h: each thread reads/writes only its own bins)
#pragma unroll
    for (int k = 0; k < BPT; k++) {
        int b = t * BPT + k;
        int ex = tbase + loc[k];
        int d_ = 0;
        if (hreg[k] > 0)
            d_ = b * CAP + atomicAdd(&cur[b], hreg[k]) - ex;
        delta[b] = d_;
        h[b] = ex;
    }
    __syncthreads();
#pragma unroll
    for (int k = 0; k < EPT; k++) {
        int idx = t + k * TPB;
        if (idx < csize) {
            int d = dreg[k];
            int s = src[c0 + idx];
            int b = d >> NBS;
            int r = atomicAdd(&h[b], 1);
            stage[r] = ((d & (NBKT - 1)) << 18) | s;
            bs[r] = (unsigned short)b;
        }
    }
    __syncthreads();
    for (int k = t; k < csize; k += TPB)
        binned[delta[bs[k]] + k] = stage[k];
}

// full-bucket counting sort, register-cached (single region read), LDS-staged
// dense csr flush. Also rowptr/rowend/dinv/xdq(bf16).
__global__ void __launch_bounds__(TPB) k_sort(
        const int* __restrict__ binned, const int* __restrict__ btot,
        const float* __restrict__ x, int* __restrict__ csr,
        int* __restrict__ rowptr, int* __restrict__ rowend,
        float* __restrict__ dinv, uint4* __restrict__ xdq, int n) {
    __shared__ int stage[CAP];     // 36 KB
    __shared__ int cnt[NBKT];
    __shared__ int curs[NBKT];
    __shared__ int wsum[NWAVE];
    int b = blockIdx.x, t = threadIdx.x;
    int base = b * CAP;
    int c = btot[b];
    cnt[t] = 0;
    __syncthreads();
    // 1) read region once into registers + histogram
    int w[RPT];
#pragma unroll
    for (int k = 0; k < RPT; k++) {
        int idx = t + k * TPB;               // coalesced
        w[k] = (idx < c) ? binned[base + idx] : -1;
        if (w[k] >= 0) atomicAdd(&cnt[w[k] >> 18], 1);
    }
    __syncthreads();
    // 2) exclusive scan of 256 bins: wave shfl scan + combine (1 barrier)
    int v = cnt[t];
    int lane = t & 63, wid = t >> 6;
    int iv = v;
#pragma unroll
    for (int off = 1; off < 64; off <<= 1) {
        int u = __shfl_up(iv, off);
        if (lane >= off) iv += u;
    }
    if (lane == 63) wsum[wid] = iv;
    __syncthreads();
    int pre = 0;
#pragma unroll
    for (int wq = 0; wq < NWAVE - 1; wq++)
        if (wid > wq) pre += wsum[wq];
    int ex = pre + iv - v;  // exclusive
    curs[t] = ex;
    // 3) per-node outputs
    int i = (b << NBS) + t;
    rowptr[i] = base + ex;
    rowend[i] = base + ex + v;
    if (i < n) {
        float di = rsqrtf((float)(v + 1));
        dinv[i] = di;
        uint4 q;
        q.x = pk2(x[i * 6 + 0] * di, x[i * 6 + 1] * di);
        q.y = pk2(x[i * 6 + 2] * di, x[i * 6 + 3] * di);
        q.z = pk2(x[i * 6 + 4] * di, x[i * 6 + 5] * di);
        q.w = 0;
        xdq[i] = q;
    }
    __syncthreads();
    // 4) scatter from registers into LDS stage (node-sorted order)
#pragma unroll
    for (int k = 0; k < RPT; k++) {
        if (w[k] >= 0) {
            int r = atomicAdd(&curs[w[k] >> 18], 1);
            stage[r] = w[k] & 0x3FFFF;
        }
    }
    __syncthreads();
    // 5) dense flush
    for (int k = t; k < c; k += TPB)
        csr[base + k] = stage[k];
}

// layer-1 gather (pre-W1 domain, bf16 payload): 16 lanes/node, 4 nodes/wave.
// epilogue: agg6 (incl self) -> @W1 -> relu(di*.+b1) -> @W2 -> *di -> g2q (bf16)
__global__ void __launch_bounds__(TPB) k_gat1(
        const uint4* __restrict__ xdq, const int* __restrict__ csr,
        const int* __restrict__ rowptr, const int* __restrict__ rowend,
        const float* __restrict__ dinv,
        const float* __restrict__ b1, const float* __restrict__ W1,
        const float* __restrict__ W2, uint2* __restrict__ g2q, int n) {
    __shared__ float w1[96];   // 6 x 16
    __shared__ float w2[128];  // 16 x 8
    __shared__ float bb[16];
    if (threadIdx.x < 96) w1[threadIdx.x] = W1[threadIdx.x];
    if (threadIdx.x < 128) w2[threadIdx.x] = W2[threadIdx.x];
    if (threadIdx.x < 16) bb[threadIdx.x] = b1[threadIdx.x];
    __syncthreads();
    int sub = threadIdx.x & 15;                    // lane within node group
    int i = blockIdx.x * 16 + (threadIdx.x >> 4);  // 16 nodes per block
    bool valid = (i < n);
    int r0 = rowptr[i], r1 = rowend[i];            // padded nodes: r0 == r1
    float a0 = 0.f, a1 = 0.f, a2 = 0.f, a3 = 0.f, a4 = 0.f, a5 = 0.f;
    float c0 = 0.f, c1 = 0.f, c2 = 0.f, c3 = 0.f, c4 = 0.f, c5 = 0.f;
    if (valid && sub == 0) {  // self-loop term
        uint4 q = xdq[i];
        a0 += BFLO(q.x); a1 += BFHI(q.x);
        a2 += BFLO(q.y); a3 += BFHI(q.y);
        a4 += BFLO(q.z); a5 += BFHI(q.z);
    }
    int j = r0 + sub;
    while (j + 16 < r1) {
        uint4 q = xdq[csr[j]];
        uint4 p = xdq[csr[j + 16]];
        a0 += BFLO(q.x); a1 += BFHI(q.x);
        a2 += BFLO(q.y); a3 += BFHI(q.y);
        a4 += BFLO(q.z); a5 += BFHI(q.z);
        c0 += BFLO(p.x); c1 += BFHI(p.x);
        c2 += BFLO(p.y); c3 += BFHI(p.y);
        c4 += BFLO(p.z); c5 += BFHI(p.z);
        j += 32;
    }
    if (j < r1) {
        uint4 q = xdq[csr[j]];
        a0 += BFLO(q.x); a1 += BFHI(q.x);
        a2 += BFLO(q.y); a3 += BFHI(q.y);
        a4 += BFLO(q.z); a5 += BFHI(q.z);
    }
    a0 += c0; a1 += c1; a2 += c2; a3 += c3; a4 += c4; a5 += c5;
#pragma unroll
    for (int m = 1; m <= 8; m <<= 1) {  // reduce within 16-lane node group
        a0 += __shfl_xor(a0, m); a1 += __shfl_xor(a1, m);
        a2 += __shfl_xor(a2, m); a3 += __shfl_xor(a3, m);
        a4 += __shfl_xor(a4, m); a5 += __shfl_xor(a5, m);
    }
    float di = valid ? dinv[i] : 0.f;
    int f = sub;  // lane = hidden feature
    float hf = a0 * w1[f] + a1 * w1[16 + f] + a2 * w1[32 + f]
             + a3 * w1[48 + f] + a4 * w1[64 + f] + a5 * w1[80 + f];
    float tf = fmaxf(di * hf + bb[f], 0.0f);
    float p0 = tf * w2[f * 8 + 0], p1 = tf * w2[f * 8 + 1];
    float p2 = tf * w2[f * 8 + 2], p3 = tf * w2[f * 8 + 3];
    float p4 = tf * w2[f * 8 + 4], p5 = tf * w2[f * 8 + 5];
    float p6 = tf * w2[f * 8 + 6], p7 = tf * w2[f * 8 + 7];
#pragma unroll
    for (int m = 1; m <= 8; m <<= 1) {  // reduce over the 16 f-lanes
        p0 += __shfl_xor(p0, m); p1 += __shfl_xor(p1, m);
        p2 += __shfl_xor(p2, m); p3 += __shfl_xor(p3, m);
        p4 += __shfl_xor(p4, m); p5 += __shfl_xor(p5, m);
        p6 += __shfl_xor(p6, m); p7 += __shfl_xor(p7, m);
    }
    if (valid && sub < 2) {
        float q0 = sub ? p4 : p0, q1 = sub ? p5 : p1;
        float q2 = sub ? p6 : p2, q3 = sub ? p7 : p3;
        uint2 o;
        o.x = pk2(q0 * di, q1 * di);
        o.y = pk2(q2 * di, q3 * di);
        g2q[i * 2 + sub] = o;
    }
}

// layer-2 gather (bf16 payload): 16 lanes/node, 4 nodes/wave.
// fused head: h = relu(dinv*agg8 + b2); out = sigmoid(h @ Wfc + bfc)
__global__ void __launch_bounds__(TPB) k_gat2(
        const uint4* __restrict__ g2q, const int* __restrict__ csr,
        const int* __restrict__ rowptr, const int* __restrict__ rowend,
        const float* __restrict__ dinv,
        const float* __restrict__ b2, const float* __restrict__ Wfc,
        const float* __restrict__ bfc, float* __restrict__ out, int n) {
    __shared__ float w[8];
    __shared__ float bb[8];
    __shared__ float bf;
    if (threadIdx.x < 8) { w[threadIdx.x] = Wfc[threadIdx.x]; bb[threadIdx.x] = b2[threadIdx.x]; }
    if (threadIdx.x == 0) bf = bfc[0];
    __syncthreads();
    int sub = threadIdx.x & 15;
    int i = blockIdx.x * 16 + (threadIdx.x >> 4);
    bool valid = (i < n);
    int r0 = rowptr[i], r1 = rowend[i];
    float a0 = 0.f, a1 = 0.f, a2 = 0.f, a3 = 0.f;
    float a4 = 0.f, a5 = 0.f, a6 = 0.f, a7 = 0.f;
    if (valid && sub == 0) {  // self-loop term
        uint4 q = g2q[i];
        a0 += BFLO(q.x); a1 += BFHI(q.x); a2 += BFLO(q.y); a3 += BFHI(q.y);
        a4 += BFLO(q.z); a5 += BFHI(q.z); a6 += BFLO(q.w); a7 += BFHI(q.w);
    }
    float c0 = 0.f, c1 = 0.f, c2 = 0.f, c3 = 0.f;
    float c4 = 0.f, c5 = 0.f, c6 = 0.f, c7 = 0.f;
    int j = r0 + sub;
    while (j + 16 < r1) {
        uint4 q = g2q[csr[j]];
        uint4 p = g2q[csr[j + 16]];
        a0 += BFLO(q.x); a1 += BFHI(q.x); a2 += BFLO(q.y); a3 += BFHI(q.y);
        a4 += BFLO(q.z); a5 += BFHI(q.z); a6 += BFLO(q.w); a7 += BFHI(q.w);
        c0 += BFLO(p.x); c1 += BFHI(p.x); c2 += BFLO(p.y); c3 += BFHI(p.y);
        c4 += BFLO(p.z); c5 += BFHI(p.z); c6 += BFLO(p.w); c7 += BFHI(p.w);
        j += 32;
    }
    if (j < r1) {
        uint4 q = g2q[csr[j]];
        a0 += BFLO(q.x); a1 += BFHI(q.x); a2 += BFLO(q.y); a3 += BFHI(q.y);
        a4 += BFLO(q.z); a5 += BFHI(q.z); a6 += BFLO(q.w); a7 += BFHI(q.w);
    }
    a0 += c0; a1 += c1; a2 += c2; a3 += c3;
    a4 += c4; a5 += c5; a6 += c6; a7 += c7;
#pragma unroll
    for (int m = 1; m <= 8; m <<= 1) {  // reduce within 16-lane node group
        a0 += __shfl_xor(a0, m); a1 += __shfl_xor(a1, m);
        a2 += __shfl_xor(a2, m); a3 += __shfl_xor(a3, m);
        a4 += __shfl_xor(a4, m); a5 += __shfl_xor(a5, m);
        a6 += __shfl_xor(a6, m); a7 += __shfl_xor(a7, m);
    }
    if (valid && sub == 0) {  // head computed once per node (cheap, no shfl)
        float di = dinv[i];
        float o = bf;
        o += fmaxf(di * a0 + bb[0], 0.0f) * w[0];
        o += fmaxf(di * a1 + bb[1], 0.0f) * w[1];
        o += fmaxf(di * a2 + bb[2], 0.0f) * w[2];
        o += fmaxf(di * a3 + bb[3], 0.0f) * w[3];
        o += fmaxf(di * a4 + bb[4], 0.0f) * w[4];
        o += fmaxf(di * a5 + bb[5], 0.0f) * w[5];
        o += fmaxf(di * a6 + bb[6], 0.0f) * w[6];
        o += fmaxf(di * a7 + bb[7], 0.0f) * w[7];
        out[i] = 1.0f / (1.0f + expf(-o));
    }
}

extern "C" void kernel_launch(void* const* d_in, const int* in_sizes, int n_in,
                              void* d_out, int out_size, void* d_ws, size_t ws_size,
                              hipStream_t stream) {
    const float* x   = (const float*)d_in[0];
    const int*   ei  = (const int*)d_in[1];
    const float* W1  = (const float*)d_in[2];
    const float* b1  = (const float*)d_in[3];
    const float* W2  = (const float*)d_in[4];
    const float* b2  = (const float*)d_in[5];
    const float* Wfc = (const float*)d_in[6];
    const float* bfc = (const float*)d_in[7];
    float* out = (float*)d_out;

    const int n = in_sizes[0] / 6;   // 200000 (<= 262144 for 18-bit packing)
    const int e = in_sizes[1] / 2;   // 6400000
    const int* src = ei;
    const int* dst = ei + e;
    const int nb = (n + NBKT - 1) >> NBS;  // 782
    const size_t np = (size_t)nb << NBS;   // padded node count (200192)
    const int nblk = (e + CHUNK - 1) / CHUNK;  // 1563 chunks
    const size_t reg = (size_t)nb * CAP;   // bucket-region total (7.2M words)

    int* cur    = (int*)d_ws;            // MAXB (doubles as btot after fillbin)
    int* binned = cur + MAXB;            // reg
    int* csr    = binned + reg;          // reg
    int* rowptr = csr + reg;             // np
    int* rowend = rowptr + np;           // np
    float* dinv = (float*)(rowend + np); // np
    uint4* xdq  = (uint4*)(dinv + np);   // np * 16 B (offset 16B-aligned)
    uint2* g2q  = (uint2*)(xdq + np);    // np * 16 B

    int gw = (n + 15) / 16;              // node-group blocks (16 nodes/block)

    hipMemsetAsync(cur, 0, MAXB * sizeof(int), stream);
    k_fillbin<<<nblk, TPB, 0, stream>>>(src, dst, cur, binned, e, nb);
    k_sort<<<nb, TPB, 0, stream>>>(binned, cur, x, csr, rowptr, rowend, dinv, xdq, n);
    k_gat1<<<gw, TPB, 0, stream>>>(xdq, csr, rowptr, rowend, dinv, b1, W1, W2, g2q, n);
    k_gat2<<<gw, TPB, 0, stream>>>((const uint4*)g2q, csr, rowptr, rowend, dinv, b2, Wfc, bfc, out, n);
}

// Round 2
// 279.276 us; speedup vs baseline: 1.1885x; 1.1885x over previous
//
#include <hip/hip_runtime.h>
#include <math.h>

// GCN 2-layer + sigmoid head. CSR pull-gather, zero fp32 atomics.
// R17: fix R16's allocation-atomic serialization.
//  - cur[] padded to 1 cache line (128 B) per bucket: per-line atomic count
//    drops 12.5K -> 1563 (no more cross-XCD line-bouncing pileup).
//  - src preloaded into registers with dst, so the LDS counting-sort phase
//    issues ZERO vmem ops -> the allocation atomicAdd returns (issued before
//    the sort) are not waited on until the delta computation after the sort.
//   k_fillbin:LDS chunk counting-sort; chunk base via atomicAdd(&cur[b*32],cnt)
//   k_sort:   full-bucket reg-cached counting sort -> dense csr, dinv, xdq(bf16)
//   k_gat1/2: node-group gathers (16 lanes/node, bf16 payloads L2-resident)

#define TPB 256
#define NBS 8
#define NBKT 256        // nodes per bucket
#define MAXB 1024       // max buckets (n <= 262144)
#define BPT (MAXB / TPB)
#define CHUNK 4096      // edges per fillbin block
#define EPT (CHUNK / TPB)
#define CAP 9216        // bucket region capacity (mean 8192 + ~11 sigma)
#define RPT (CAP / TPB) // 36 register-cached words per k_sort thread
#define NWAVE (TPB / 64)
#define CSTR 32         // cur[] stride in ints: 128 B = 1 line per bucket

__device__ __forceinline__ unsigned short f2bf(float f) {
    unsigned u = __float_as_uint(f);
    unsigned r = (u + 0x7FFFu + ((u >> 16) & 1u)) >> 16;  // RNE
    return (unsigned short)r;
}
__device__ __forceinline__ unsigned pk2(float a, float b) {
    return (unsigned)f2bf(a) | ((unsigned)f2bf(b) << 16);
}
#define BFLO(u) __uint_as_float((u) << 16)
#define BFHI(u) __uint_as_float((u) & 0xFFFF0000u)

// bin edges into fixed-cap bucket regions. LDS counting sort of the chunk;
// chunk's base in each bucket region via one global atomicAdd per non-empty
// bucket (padded line per bucket; returns consumed only after the LDS sort).
// word: ((d&255)<<18)|s
__global__ void __launch_bounds__(TPB) k_fillbin(
        const int* __restrict__ src, const int* __restrict__ dst,
        int* __restrict__ cur, int* __restrict__ binned, int e, int nb) {
    __shared__ int stage[CHUNK];            // 16 KB, bucket-sorted packed words
    __shared__ unsigned short bs[CHUNK];    // 8 KB, bucket id per sorted slot
    __shared__ int h[MAXB];                 // 4 KB, hist -> stage cursor
    __shared__ int delta[MAXB];             // 4 KB
    __shared__ int wsum[NWAVE];
    int t = threadIdx.x;
    int c0 = blockIdx.x * CHUNK;
    int csize = min(e - c0, CHUNK);
#pragma unroll
    for (int k = 0; k < BPT; k++) h[t * BPT + k] = 0;
    __syncthreads();
    int dreg[EPT], sreg[EPT];
#pragma unroll
    for (int k = 0; k < EPT; k++) {
        int idx = t + k * TPB;               // coalesced
        int d = (idx < csize) ? dst[c0 + idx] : -1;
        int s = (idx < csize) ? src[c0 + idx] : 0;
        dreg[k] = d;
        sreg[k] = s;
        if (d >= 0) atomicAdd(&h[d >> NBS], 1);
    }
    __syncthreads();
    // per-thread local prefix over its BPT bins
    int loc[BPT], hreg[BPT];
    int ts = 0;
#pragma unroll
    for (int k = 0; k < BPT; k++) {
        hreg[k] = h[t * BPT + k];
        loc[k] = ts;
        ts += hreg[k];
    }
    // block-wide inclusive scan of ts: wave shfl scan + wave-sum combine
    int lane = t & 63, wid = t >> 6;
    int v = ts;
#pragma unroll
    for (int off = 1; off < 64; off <<= 1) {
        int u = __shfl_up(v, off);
        if (lane >= off) v += u;
    }
    if (lane == 63) wsum[wid] = v;
    __syncthreads();
    int pre = 0;
#pragma unroll
    for (int wq = 0; wq < NWAVE - 1; wq++)
        if (wid > wq) pre += wsum[wq];
    int tbase = pre + v - ts;  // exclusive prefix for this thread's first bin
    // issue allocation atomics NOW; returns are not consumed until after the
    // LDS sort (which is vmem-free), hiding the contended-return latency.
    int myex[BPT], myret[BPT];
#pragma unroll
    for (int k = 0; k < BPT; k++) {
        int b = t * BPT + k;
        int ex = tbase + loc[k];
        myex[k] = ex;
        h[b] = ex;  // stage cursor (own bins only; barrier below publishes)
        myret[k] = (hreg[k] > 0) ? atomicAdd(&cur[(size_t)b * CSTR], hreg[k]) : 0;
    }
    __syncthreads();
    // LDS counting sort of the chunk (registers -> LDS only, no vmem)
#pragma unroll
    for (int k = 0; k < EPT; k++) {
        int d = dreg[k];
        if (d >= 0) {
            int b = d >> NBS;
            int r = atomicAdd(&h[b], 1);
            stage[r] = ((d & (NBKT - 1)) << 18) | sreg[k];
            bs[r] = (unsigned short)b;
        }
    }
    // consume atomic returns (first vmcnt wait on them lands here)
#pragma unroll
    for (int k = 0; k < BPT; k++) {
        int b = t * BPT + k;
        delta[b] = (hreg[k] > 0) ? (b * CAP + myret[k] - myex[k]) : 0;
    }
    __syncthreads();
    for (int k = t; k < csize; k += TPB)
        binned[delta[bs[k]] + k] = stage[k];
}

// full-bucket counting sort, register-cached (single region read), LDS-staged
// dense csr flush. Also rowptr/rowend/dinv/xdq(bf16).
__global__ void __launch_bounds__(TPB) k_sort(
        const int* __restrict__ binned, const int* __restrict__ btot,
        const float* __restrict__ x, int* __restrict__ csr,
        int* __restrict__ rowptr, int* __restrict__ rowend,
        float* __restrict__ dinv, uint4* __restrict__ xdq, int n) {
    __shared__ int stage[CAP];     // 36 KB
    __shared__ int cnt[NBKT];
    __shared__ int curs[NBKT];
    __shared__ int wsum[NWAVE];
    int b = blockIdx.x, t = threadIdx.x;
    int base = b * CAP;
    int c = btot[(size_t)b * CSTR];
    cnt[t] = 0;
    __syncthreads();
    // 1) read region once into registers + histogram
    int w[RPT];
#pragma unroll
    for (int k = 0; k < RPT; k++) {
        int idx = t + k * TPB;               // coalesced
        w[k] = (idx < c) ? binned[base + idx] : -1;
        if (w[k] >= 0) atomicAdd(&cnt[w[k] >> 18], 1);
    }
    __syncthreads();
    // 2) exclusive scan of 256 bins: wave shfl scan + combine (1 barrier)
    int v = cnt[t];
    int lane = t & 63, wid = t >> 6;
    int iv = v;
#pragma unroll
    for (int off = 1; off < 64; off <<= 1) {
        int u = __shfl_up(iv, off);
        if (lane >= off) iv += u;
    }
    if (lane == 63) wsum[wid] = iv;
    __syncthreads();
    int pre = 0;
#pragma unroll
    for (int wq = 0; wq < NWAVE - 1; wq++)
        if (wid > wq) pre += wsum[wq];
    int ex = pre + iv - v;  // exclusive
    curs[t] = ex;
    // 3) per-node outputs
    int i = (b << NBS) + t;
    rowptr[i] = base + ex;
    rowend[i] = base + ex + v;
    if (i < n) {
        float di = rsqrtf((float)(v + 1));
        dinv[i] = di;
        uint4 q;
        q.x = pk2(x[i * 6 + 0] * di, x[i * 6 + 1] * di);
        q.y = pk2(x[i * 6 + 2] * di, x[i * 6 + 3] * di);
        q.z = pk2(x[i * 6 + 4] * di, x[i * 6 + 5] * di);
        q.w = 0;
        xdq[i] = q;
    }
    __syncthreads();
    // 4) scatter from registers into LDS stage (node-sorted order)
#pragma unroll
    for (int k = 0; k < RPT; k++) {
        if (w[k] >= 0) {
            int r = atomicAdd(&curs[w[k] >> 18], 1);
            stage[r] = w[k] & 0x3FFFF;
        }
    }
    __syncthreads();
    // 5) dense flush
    for (int k = t; k < c; k += TPB)
        csr[base + k] = stage[k];
}

// layer-1 gather (pre-W1 domain, bf16 payload): 16 lanes/node, 4 nodes/wave.
// epilogue: agg6 (incl self) -> @W1 -> relu(di*.+b1) -> @W2 -> *di -> g2q (bf16)
__global__ void __launch_bounds__(TPB) k_gat1(
        const uint4* __restrict__ xdq, const int* __restrict__ csr,
        const int* __restrict__ rowptr, const int* __restrict__ rowend,
        const float* __restrict__ dinv,
        const float* __restrict__ b1, const float* __restrict__ W1,
        const float* __restrict__ W2, uint2* __restrict__ g2q, int n) {
    __shared__ float w1[96];   // 6 x 16
    __shared__ float w2[128];  // 16 x 8
    __shared__ float bb[16];
    if (threadIdx.x < 96) w1[threadIdx.x] = W1[threadIdx.x];
    if (threadIdx.x < 128) w2[threadIdx.x] = W2[threadIdx.x];
    if (threadIdx.x < 16) bb[threadIdx.x] = b1[threadIdx.x];
    __syncthreads();
    int sub = threadIdx.x & 15;                    // lane within node group
    int i = blockIdx.x * 16 + (threadIdx.x >> 4);  // 16 nodes per block
    bool valid = (i < n);
    int r0 = rowptr[i], r1 = rowend[i];            // padded nodes: r0 == r1
    float a0 = 0.f, a1 = 0.f, a2 = 0.f, a3 = 0.f, a4 = 0.f, a5 = 0.f;
    float c0 = 0.f, c1 = 0.f, c2 = 0.f, c3 = 0.f, c4 = 0.f, c5 = 0.f;
    if (valid && sub == 0) {  // self-loop term
        uint4 q = xdq[i];
        a0 += BFLO(q.x); a1 += BFHI(q.x);
        a2 += BFLO(q.y); a3 += BFHI(q.y);
        a4 += BFLO(q.z); a5 += BFHI(q.z);
    }
    int j = r0 + sub;
    while (j + 16 < r1) {
        uint4 q = xdq[csr[j]];
        uint4 p = xdq[csr[j + 16]];
        a0 += BFLO(q.x); a1 += BFHI(q.x);
        a2 += BFLO(q.y); a3 += BFHI(q.y);
        a4 += BFLO(q.z); a5 += BFHI(q.z);
        c0 += BFLO(p.x); c1 += BFHI(p.x);
        c2 += BFLO(p.y); c3 += BFHI(p.y);
        c4 += BFLO(p.z); c5 += BFHI(p.z);
        j += 32;
    }
    if (j < r1) {
        uint4 q = xdq[csr[j]];
        a0 += BFLO(q.x); a1 += BFHI(q.x);
        a2 += BFLO(q.y); a3 += BFHI(q.y);
        a4 += BFLO(q.z); a5 += BFHI(q.z);
    }
    a0 += c0; a1 += c1; a2 += c2; a3 += c3; a4 += c4; a5 += c5;
#pragma unroll
    for (int m = 1; m <= 8; m <<= 1) {  // reduce within 16-lane node group
        a0 += __shfl_xor(a0, m); a1 += __shfl_xor(a1, m);
        a2 += __shfl_xor(a2, m); a3 += __shfl_xor(a3, m);
        a4 += __shfl_xor(a4, m); a5 += __shfl_xor(a5, m);
    }
    float di = valid ? dinv[i] : 0.f;
    int f = sub;  // lane = hidden feature
    float hf = a0 * w1[f] + a1 * w1[16 + f] + a2 * w1[32 + f]
             + a3 * w1[48 + f] + a4 * w1[64 + f] + a5 * w1[80 + f];
    float tf = fmaxf(di * hf + bb[f], 0.0f);
    float p0 = tf * w2[f * 8 + 0], p1 = tf * w2[f * 8 + 1];
    float p2 = tf * w2[f * 8 + 2], p3 = tf * w2[f * 8 + 3];
    float p4 = tf * w2[f * 8 + 4], p5 = tf * w2[f * 8 + 5];
    float p6 = tf * w2[f * 8 + 6], p7 = tf * w2[f * 8 + 7];
#pragma unroll
    for (int m = 1; m <= 8; m <<= 1) {  // reduce over the 16 f-lanes
        p0 += __shfl_xor(p0, m); p1 += __shfl_xor(p1, m);
        p2 += __shfl_xor(p2, m); p3 += __shfl_xor(p3, m);
        p4 += __shfl_xor(p4, m); p5 += __shfl_xor(p5, m);
        p6 += __shfl_xor(p6, m); p7 += __shfl_xor(p7, m);
    }
    if (valid && sub < 2) {
        float q0 = sub ? p4 : p0, q1 = sub ? p5 : p1;
        float q2 = sub ? p6 : p2, q3 = sub ? p7 : p3;
        uint2 o;
        o.x = pk2(q0 * di, q1 * di);
        o.y = pk2(q2 * di, q3 * di);
        g2q[i * 2 + sub] = o;
    }
}

// layer-2 gather (bf16 payload): 16 lanes/node, 4 nodes/wave.
// fused head: h = relu(dinv*agg8 + b2); out = sigmoid(h @ Wfc + bfc)
__global__ void __launch_bounds__(TPB) k_gat2(
        const uint4* __restrict__ g2q, const int* __restrict__ csr,
        const int* __restrict__ rowptr, const int* __restrict__ rowend,
        const float* __restrict__ dinv,
        const float* __restrict__ b2, const float* __restrict__ Wfc,
        const float* __restrict__ bfc, float* __restrict__ out, int n) {
    __shared__ float w[8];
    __shared__ float bb[8];
    __shared__ float bf;
    if (threadIdx.x < 8) { w[threadIdx.x] = Wfc[threadIdx.x]; bb[threadIdx.x] = b2[threadIdx.x]; }
    if (threadIdx.x == 0) bf = bfc[0];
    __syncthreads();
    int sub = threadIdx.x & 15;
    int i = blockIdx.x * 16 + (threadIdx.x >> 4);
    bool valid = (i < n);
    int r0 = rowptr[i], r1 = rowend[i];
    float a0 = 0.f, a1 = 0.f, a2 = 0.f, a3 = 0.f;
    float a4 = 0.f, a5 = 0.f, a6 = 0.f, a7 = 0.f;
    if (valid && sub == 0) {  // self-loop term
        uint4 q = g2q[i];
        a0 += BFLO(q.x); a1 += BFHI(q.x); a2 += BFLO(q.y); a3 += BFHI(q.y);
        a4 += BFLO(q.z); a5 += BFHI(q.z); a6 += BFLO(q.w); a7 += BFHI(q.w);
    }
    float c0 = 0.f, c1 = 0.f, c2 = 0.f, c3 = 0.f;
    float c4 = 0.f, c5 = 0.f, c6 = 0.f, c7 = 0.f;
    int j = r0 + sub;
    while (j + 16 < r1) {
        uint4 q = g2q[csr[j]];
        uint4 p = g2q[csr[j + 16]];
        a0 += BFLO(q.x); a1 += BFHI(q.x); a2 += BFLO(q.y); a3 += BFHI(q.y);
        a4 += BFLO(q.z); a5 += BFHI(q.z); a6 += BFLO(q.w); a7 += BFHI(q.w);
        c0 += BFLO(p.x); c1 += BFHI(p.x); c2 += BFLO(p.y); c3 += BFHI(p.y);
        c4 += BFLO(p.z); c5 += BFHI(p.z); c6 += BFLO(p.w); c7 += BFHI(p.w);
        j += 32;
    }
    if (j < r1) {
        uint4 q = g2q[csr[j]];
        a0 += BFLO(q.x); a1 += BFHI(q.x); a2 += BFLO(q.y); a3 += BFHI(q.y);
        a4 += BFLO(q.z); a5 += BFHI(q.z); a6 += BFLO(q.w); a7 += BFHI(q.w);
    }
    a0 += c0; a1 += c1; a2 += c2; a3 += c3;
    a4 += c4; a5 += c5; a6 += c6; a7 += c7;
#pragma unroll
    for (int m = 1; m <= 8; m <<= 1) {  // reduce within 16-lane node group
        a0 += __shfl_xor(a0, m); a1 += __shfl_xor(a1, m);
        a2 += __shfl_xor(a2, m); a3 += __shfl_xor(a3, m);
        a4 += __shfl_xor(a4, m); a5 += __shfl_xor(a5, m);
        a6 += __shfl_xor(a6, m); a7 += __shfl_xor(a7, m);
    }
    if (valid && sub == 0) {  // head computed once per node (cheap, no shfl)
        float di = dinv[i];
        float o = bf;
        o += fmaxf(di * a0 + bb[0], 0.0f) * w[0];
        o += fmaxf(di * a1 + bb[1], 0.0f) * w[1];
        o += fmaxf(di * a2 + bb[2], 0.0f) * w[2];
        o += fmaxf(di * a3 + bb[3], 0.0f) * w[3];
        o += fmaxf(di * a4 + bb[4], 0.0f) * w[4];
        o += fmaxf(di * a5 + bb[5], 0.0f) * w[5];
        o += fmaxf(di * a6 + bb[6], 0.0f) * w[6];
        o += fmaxf(di * a7 + bb[7], 0.0f) * w[7];
        out[i] = 1.0f / (1.0f + expf(-o));
    }
}

extern "C" void kernel_launch(void* const* d_in, const int* in_sizes, int n_in,
                              void* d_out, int out_size, void* d_ws, size_t ws_size,
                              hipStream_t stream) {
    const float* x   = (const float*)d_in[0];
    const int*   ei  = (const int*)d_in[1];
    const float* W1  = (const float*)d_in[2];
    const float* b1  = (const float*)d_in[3];
    const float* W2  = (const float*)d_in[4];
    const float* b2  = (const float*)d_in[5];
    const float* Wfc = (const float*)d_in[6];
    const float* bfc = (const float*)d_in[7];
    float* out = (float*)d_out;

    const int n = in_sizes[0] / 6;   // 200000 (<= 262144 for 18-bit packing)
    const int e = in_sizes[1] / 2;   // 6400000
    const int* src = ei;
    const int* dst = ei + e;
    const int nb = (n + NBKT - 1) >> NBS;  // 782
    const size_t np = (size_t)nb << NBS;   // padded node count (200192)
    const int nblk = (e + CHUNK - 1) / CHUNK;  // 1563 chunks
    const size_t reg = (size_t)nb * CAP;   // bucket-region total (7.2M words)

    int* cur    = (int*)d_ws;            // MAXB * CSTR (doubles as btot)
    int* binned = cur + (size_t)MAXB * CSTR;  // reg
    int* csr    = binned + reg;          // reg
    int* rowptr = csr + reg;             // np
    int* rowend = rowptr + np;           // np
    float* dinv = (float*)(rowend + np); // np
    uint4* xdq  = (uint4*)(dinv + np);   // np * 16 B (offset 16B-aligned)
    uint2* g2q  = (uint2*)(xdq + np);    // np * 16 B

    int gw = (n + 15) / 16;              // node-group blocks (16 nodes/block)

    hipMemsetAsync(cur, 0, (size_t)MAXB * CSTR * sizeof(int), stream);
    k_fillbin<<<nblk, TPB, 0, stream>>>(src, dst, cur, binned, e, nb);
    k_sort<<<nb, TPB, 0, stream>>>(binned, cur, x, csr, rowptr, rowend, dinv, xdq, n);
    k_gat1<<<gw, TPB, 0, stream>>>(xdq, csr, rowptr, rowend, dinv, b1, W1, W2, g2q, n);
    k_gat2<<<gw, TPB, 0, stream>>>((const uint4*)g2q, csr, rowptr, rowend, dinv, b2, Wfc, bfc, out, n);
}